// Round 13
// baseline (123.412 us; speedup 1.0000x reference)
//
#include <hip/hip_runtime.h>
#include <math.h>

// CTC loss forward: T=1024, N=128, C=256, S=64, L=2S+1=129, blank=0.
constexpr int kT = 1024;
constexpr int kN = 128;
constexpr int kC = 256;
constexpr float NEGV = -1e30f;
constexpr int kRow = 260;            // floats per t4-group: 65 states x 4 t's
constexpr int kRowB = kRow * 4;      // 1040 bytes
constexpr int kCH = 32;              // t-steps per chunk per direction
constexpr int kNCH = 512 / kCH;      // 16 chunks per direction
constexpr int kChF = 8 * kRow;       // 2080 floats per chunk (8 t4-groups)
constexpr int kChB = kChF * 4;       // 8320 bytes
constexpr float LOG2E = 1.4426950408889634f;
constexpr float LN2 = 0.6931471805599453f;

#if __has_builtin(__builtin_amdgcn_exp2f)
#define EXP2(x) __builtin_amdgcn_exp2f(x)
#else
#define EXP2(x) exp2f(x)
#endif
#if __has_builtin(__builtin_amdgcn_logf)
#define LOG2(x) __builtin_amdgcn_logf(x)
#else
#define LOG2(x) log2f(x)
#endif

struct TrueT { static constexpr bool value = true; };

__device__ __forceinline__ float lse2_2(float a, float b) {  // log2(2^a + 2^b)
    const float m = fmaxf(a, b);
    const float d = fminf(a, b) - m;
    return m + LOG2(1.0f + EXP2(d));
}

__device__ __forceinline__ float lse2_e(float a, float b) {  // ln(e^a + e^b)
    const float m = fmaxf(a, b);
    return m + __logf(1.0f + __expf(fminf(a, b) - m));
}

__device__ __forceinline__ float lse3_e(float a, float b, float c) {
    const float m = fmaxf(fmaxf(a, b), c);
    return m + __logf(__expf(a - m) + __expf(b - m) + __expf(c - m));
}

// Kernel 1: per-row logsumexp over C=256. GATHER mode: block = (n, t4) covers
// 4 consecutive t for one n; writes BASE-2 log-probs in blocked-transposed
// layout lpg[n][t4][s][j] (s=0 blank, s=1+k label k; j=t&3), coalesced via LDS.
template <bool GATHER>
__global__ __launch_bounds__(256) void k_lse(const float* __restrict__ logits,
                                             const int* __restrict__ y,
                                             float* __restrict__ lpg,
                                             float* __restrict__ lse_out) {
    __shared__ float srow[4][kC];
    __shared__ float sT[4][65];
    const int w = threadIdx.x >> 6;
    const int lane = threadIdx.x & 63;
    const int n = blockIdx.x & (kN - 1);
    const int t4 = blockIdx.x >> 7;
    const int t = t4 * 4 + w;
    const int row = t * kN + n;

    const float4 v = reinterpret_cast<const float4*>(logits + (size_t)row * kC)[lane];
    float m = fmaxf(fmaxf(v.x, v.y), fmaxf(v.z, v.w));
#pragma unroll
    for (int o = 32; o > 0; o >>= 1) m = fmaxf(m, __shfl_xor(m, o));
    float s = __expf(v.x - m) + __expf(v.y - m) + __expf(v.z - m) + __expf(v.w - m);
#pragma unroll
    for (int o = 32; o > 0; o >>= 1) s += __shfl_xor(s, o);

    if (GATHER) {
        const float log2s = LOG2(s);
        float* sr = srow[w];
        reinterpret_cast<float4*>(sr)[lane] = v;
        const int cls = y[(n << 6) + lane];  // labels in [1, C)
        sT[w][1 + lane] = (sr[cls] - m) * LOG2E - log2s;
        if (lane == 0) sT[w][0] = (v.x - m) * LOG2E - log2s;  // blank
        __syncthreads();
        float* op = lpg + (size_t)n * (kT / 4) * kRow + (size_t)t4 * kRow;
        const int tid = threadIdx.x;
        op[tid] = sT[tid & 3][tid >> 2];            // idx = s*4 + j
        if (tid < 4) op[256 + tid] = sT[tid][64];   // s = 64, j = tid
    } else {
        if (lane == 0) lse_out[row] = m + __logf(s);
    }
}

// row_shr:1 with readlane-fed boundaries (validated r6/r7): lane l <- x[l-1];
// lane 0 <- x[63] (wrap); row heads 16/32/48 <- x[15/31/47].
__device__ __forceinline__ float row_shr1_b(float x, int lgrp) {
    const int xi = __float_as_int(x);
    const int b15 = __builtin_amdgcn_readlane(xi, 15);
    const int b31 = __builtin_amdgcn_readlane(xi, 31);
    const int b47 = __builtin_amdgcn_readlane(xi, 47);
    const int b63 = __builtin_amdgcn_readlane(xi, 63);
    const int bnd = (lgrp == 0) ? b63 : (lgrp == 1) ? b15 : (lgrp == 2) ? b31 : b47;
    return __int_as_float(__builtin_amdgcn_update_dpp(bnd, xi, 0x111, 0xF, 0xF, false));
}

// One DP step, log2 domain (validated r7/r11): used for guarded chunks.
template <bool FRZ>
__device__ __forceinline__ void dp_step(float& A, float& B, float& C,
                                        float lpb, float lpy, bool skip,
                                        int lgrp, int l, bool commit) {
    const float am1 = row_shr1_b(B, lgrp);
    const float am1s = skip ? am1 : NEGV;
    const float x = fmaxf(B, A), yv = fminf(B, A);
    const float mB = fmaxf(x, am1s);
    const float dB1 = fmaxf(yv, fminf(x, am1s)) - mB;
    const float dB2 = fminf(yv, am1s) - mB;
    const float nB = (lpy + mB) + LOG2(1.0f + (EXP2(dB1) + EXP2(dB2)));
    const float u = (l == 0) ? C : A;
    const float mA = fmaxf(u, am1);
    const float lseA = mA + LOG2(1.0f + EXP2(fminf(u, am1) - mA));
    const float nA = lpb + ((l == 0) ? A : lseA);
    const float nC = lpb + lseA;
    if (FRZ) {
        A = commit ? nA : A;
        B = commit ? nB : B;
        C = commit ? nC : C;
    } else {
        A = nA; B = nB; C = nC;
    }
}

// 2-step window: applies dp_step twice algebraically. Path weights (E*, O*)
// depend only on lp values -> computed off the serial chain. Chain = 3 chained
// row_shr1 + one 4-term and one 5-term lse.
// lpy0m1 = lpy0 of lane l-1 (lane 0: lpy0[63] — feeds the extra state's path).
__device__ __forceinline__ void win_step(float& A, float& B, float& C,
                                         float lpb0, float lpy0, float lpb1,
                                         float lpy1, float lpy0m1, float skf,
                                         float skm1f, float og2, float og4,
                                         float e3g, int lgrp, int l) {
    // ---- weights (off-chain) ----
    const float E0 = lpb0 + lpb1;
    const float E1 = lpb1 + lse2_2(lpb0, lpy0m1);
    const float E2 = lpb1 + lpy0m1;
    const float E3 = E2 + skm1f + e3g;  // e3g: lane 1 has no state -1
    const float O0 = lpy1 + lpy0;
    const float O1 = lpy1 + lse2_2(lpy0, lpb0);
    const float p0 = lpb0, p1 = skf + lpy0m1, p2 = skf + lpy0;
    const float mx = fmaxf(fmaxf(p0, p1), p2);
    const float md = fmaxf(fminf(p0, p1), fminf(fmaxf(p0, p1), p2));
    const float mn = fminf(fminf(p0, p1), p2);
    const float O2 = lpy1 + og2 + (mx + LOG2(1.0f + EXP2(md - mx) + EXP2(mn - mx)));
    const float O3 = lpy1 + og2 + skf + lpy0m1;
    const float O4 = lpy1 + og4 + skf + skm1f + lpy0m1;
    // ---- serial chain ----
    const float s1A = row_shr1_b(A, lgrp);      // alpha[2m-2]
    const float s1B = row_shr1_b(B, lgrp);      // alpha[2m-1]
    const float s2B = row_shr1_b(s1B, lgrp);    // alpha[2m-3]
    // even path (lanes>=1: state 2m; lane 0: extra state via u=C)
    const float u = (l == 0) ? C : A;
    const float q0 = E0 + u, q1 = E1 + s1B, q2 = E2 + s1A, q3 = E3 + s2B;
    const float mE = fmaxf(fmaxf(q0, q1), fmaxf(q2, q3));
    const float sE = (EXP2(q0 - mE) + EXP2(q1 - mE)) + (EXP2(q2 - mE) + EXP2(q3 - mE));
    const float lseE = mE + LOG2(sE);
    const float nA = (l == 0) ? (E0 + A) : lseE;  // state 0: self-path only
    const float nC = lseE;                        // meaningful at lane 0
    // odd path (state 2m+1)
    const float r0 = O0 + B, r1 = O1 + A, r2 = O2 + s1B, r3 = O3 + s1A, r4 = O4 + s2B;
    const float mO = fmaxf(fmaxf(fmaxf(r0, r1), fmaxf(r2, r3)), r4);
    const float sO = (EXP2(r0 - mO) + EXP2(r1 - mO)) +
                     (EXP2(r2 - mO) + EXP2(r3 - mO)) + EXP2(r4 - mO);
    const float nB = mO + LOG2(sO);
    A = nA; B = nB; C = nC;
}

// Kernel 2: split fwd/bwd DP with 2-step windows. One block per batch item,
// 8 waves: w0 = alpha (t=1..511), w1 = beta (t=1023..512, reversed lane map),
// w2-4 / w5-7 DMA-stage the fwd / bwd lp streams.
__global__ __launch_bounds__(512) void k_dp_split(const float* __restrict__ lpg,
                                                  const int* __restrict__ y,
                                                  const int* __restrict__ xlens,
                                                  const int* __restrict__ ylens,
                                                  float* __restrict__ nll_out) {
    __shared__ alignas(16) float sbf[2][kChF];
    __shared__ alignas(16) float sbb[2][kChF];
    __shared__ float st_f[130];
    __shared__ float st_b[130];
    const int n = blockIdx.x;
    const int wid = threadIdx.x >> 6;
    const int l = threadIdx.x & 63;
    const int lgrp = l >> 4;
    const char* src = (const char*)(lpg + (size_t)n * (kT / 4) * kRow);

    auto stage = [&](int c, int b, bool isF) {
        const int widx = isF ? (wid - 2) : (wid - 5);
        const long off = isF ? (long)c * kChB : (long)(256 - 8 * (c + 1)) * kRowB;
        const char* gs = src + off;
        char* ls = (char*)(isF ? &sbf[b][0] : &sbb[b][0]);
#pragma unroll
        for (int r = 0; r < 3; ++r) {
            const int wi = widx * 64 + r * 192;  // wave-uniform word index
            if (wi + l < kChB / 16) {
                __builtin_amdgcn_global_load_lds(
                    (const __attribute__((address_space(1))) void*)(gs + (size_t)(wi + l) * 16),
                    (__attribute__((address_space(3))) void*)(ls + (size_t)wi * 16), 16, 0, 0);
            }
        }
    };

    if (wid >= 2) stage(0, 0, wid < 5);
    __syncthreads();

    const int yl = ylens[n];
    const int xl = xlens[n];
    const float og2 = (l >= 1) ? 0.0f : NEGV;
    const float og4 = (l >= 2) ? 0.0f : NEGV;
    const float e3g = (l == 1) ? NEGV : 0.0f;

    if (wid == 0) {
        // ---------------- FORWARD: alpha, t = 1..511 ----------------
        const int ycur = y[(n << 6) + l];
        const int yprev = __shfl_up(ycur, 1);
        const bool skip = (l >= 1) && (ycur != yprev);
        const float skf = skip ? 0.0f : NEGV;
        const float skm1f = __shfl(skf, (l + 63) & 63);  // lane0 <- skf[63]
        const int im1f = (l == 0) ? 256 : 4 * l;         // lpy[m-1] word offset

        float aA = (l == 0) ? sbf[0][0] : NEGV;  // lp[t=0][s=0]
        float aB = (l == 0) ? sbf[0][4] : NEGV;  // lp[t=0][s=1]
        float aC = NEGV;

        for (int c = 0; c < kNCH; ++c) {
            const float* B = sbf[c & 1];
            const int tb0 = c * kCH;
            if (c == 0 || tb0 + kCH - 1 >= xl) {
                // guarded 1-step chunk (r11-validated)
                float pb[2][4][4], py[2][4][4];
#define LOADF(H, D)                                                          \
    do {                                                                     \
        _Pragma("unroll") for (int q_ = 0; q_ < 4; ++q_) {                   \
            const int rb_ = (4 * (H) + q_) * kRow;                           \
            const float4 t0_ = *(const float4*)&B[rb_];                      \
            const float4 t1_ = *(const float4*)&B[rb_ + 4 + 4 * l];          \
            pb[D][q_][0] = t0_.x; pb[D][q_][1] = t0_.y;                      \
            pb[D][q_][2] = t0_.z; pb[D][q_][3] = t0_.w;                      \
            py[D][q_][0] = t1_.x; py[D][q_][1] = t1_.y;                      \
            py[D][q_][2] = t1_.z; py[D][q_][3] = t1_.w;                      \
        }                                                                    \
    } while (0)
                LOADF(0, 0);
#pragma unroll
                for (int h = 0; h < 2; ++h) {
                    if (h < 1) LOADF(1, 1);
#pragma unroll
                    for (int q = 0; q < 4; ++q) {
#pragma unroll
                        for (int j = 0; j < 4; ++j) {
                            const int t = tb0 + 16 * h + 4 * q + j;
                            dp_step<true>(aA, aB, aC, pb[h][q][j], py[h][q][j],
                                          skip, lgrp, l, (t > 0) & (t < xl));
                        }
                    }
                }
#undef LOADF
            } else {
                // fast 2-step windows (16 per chunk)
                float pb[2][4][4], py[2][4][4], ph[2][4][4];
#define LOADW(H, D)                                                          \
    do {                                                                     \
        _Pragma("unroll") for (int q_ = 0; q_ < 4; ++q_) {                   \
            const int rb_ = (4 * (H) + q_) * kRow;                           \
            const float4 t0_ = *(const float4*)&B[rb_];                      \
            const float4 t1_ = *(const float4*)&B[rb_ + 4 + 4 * l];          \
            const float4 t2_ = *(const float4*)&B[rb_ + im1f];               \
            pb[D][q_][0] = t0_.x; pb[D][q_][1] = t0_.y;                      \
            pb[D][q_][2] = t0_.z; pb[D][q_][3] = t0_.w;                      \
            py[D][q_][0] = t1_.x; py[D][q_][1] = t1_.y;                      \
            py[D][q_][2] = t1_.z; py[D][q_][3] = t1_.w;                      \
            ph[D][q_][0] = t2_.x; ph[D][q_][1] = t2_.y;                      \
            ph[D][q_][2] = t2_.z; ph[D][q_][3] = t2_.w;                      \
        }                                                                    \
    } while (0)
                LOADW(0, 0);
#pragma unroll
                for (int h = 0; h < 2; ++h) {
                    if (h < 1) LOADW(1, 1);
#pragma unroll
                    for (int q = 0; q < 4; ++q) {
                        win_step(aA, aB, aC, pb[h][q][0], py[h][q][0],
                                 pb[h][q][1], py[h][q][1], ph[h][q][0], skf,
                                 skm1f, og2, og4, e3g, lgrp, l);
                        win_step(aA, aB, aC, pb[h][q][2], py[h][q][2],
                                 pb[h][q][3], py[h][q][3], ph[h][q][2], skf,
                                 skm1f, og2, og4, e3g, lgrp, l);
                    }
                }
#undef LOADW
            }
            __syncthreads();
        }
        st_f[2 * l] = aA;
        st_f[2 * l + 1] = aB;
        if (l == 0) st_f[128] = aC;
        __syncthreads();

        // ---------------- MERGE ----------------
        const float v0 = st_f[l] + st_b[l];
        const float v1 = st_f[64 + l] + st_b[64 + l];
        const float v2 = (l == 0) ? (st_f[128] + st_b[128]) : NEGV;
        float mm = fmaxf(fmaxf(v0, v1), v2);
#pragma unroll
        for (int o = 32; o > 0; o >>= 1) mm = fmaxf(mm, __shfl_xor(mm, o));
        float sm = EXP2(v0 - mm) + EXP2(v1 - mm) + EXP2(v2 - mm);
#pragma unroll
        for (int o = 32; o > 0; o >>= 1) sm += __shfl_xor(sm, o);
        if (l == 0) {
            float nll;
            if (xl <= 512) {  // beta segment empty: read frozen alpha directly
                nll = -lse2_2(st_f[2 * yl], st_f[2 * yl - 1]) * LN2;
            } else {
                nll = -(mm + LOG2(sm)) * LN2;
            }
            if (!(isfinite(nll) && nll < 1e29f)) nll = 0.0f;  // zero_infinity
            nll_out[n] = nll / (float)yl;
        }
    } else if (wid == 1) {
        // ---------------- BACKWARD: beta, t = 1023..512 (reversed lanes) ----
        const int ycb = y[(n << 6) + 63 - l];     // label of state 127-2l
        const int yup = __shfl_up(ycb, 1);
        const bool skipb = (l >= 1) && (ycb != yup);
        const float skf = skipb ? 0.0f : NEGV;
        const float skm1f = __shfl(skf, (l + 63) & 63);
        const int im1b = (l == 0) ? 4 : 260 - 4 * l;  // reversed lpy[m-1] offset
        const int ls = 64 - yl;                        // seed lane
        float bA = NEGV, bB = NEGV, b0 = NEGV;

        for (int c = 0; c < kNCH; ++c) {
            const float* B = sbb[c & 1];
            const int ttop = 1023 - kCH * c;
            if (ttop >= xl - 1) {
                // guarded 1-step chunk (r11-validated, with in-stream seed)
                float pb[2][4][4], py[2][4][4];
#define LOADB(H, D)                                                          \
    do {                                                                     \
        _Pragma("unroll") for (int q_ = 0; q_ < 4; ++q_) {                   \
            const int rb_ = (7 - 4 * (H) - q_) * kRow;                       \
            const float4 t0_ = *(const float4*)&B[rb_];                      \
            const float4 t1_ = *(const float4*)&B[rb_ + 256 - 4 * l];        \
            pb[D][q_][0] = t0_.x; pb[D][q_][1] = t0_.y;                      \
            pb[D][q_][2] = t0_.z; pb[D][q_][3] = t0_.w;                      \
            py[D][q_][0] = t1_.x; py[D][q_][1] = t1_.y;                      \
            py[D][q_][2] = t1_.z; py[D][q_][3] = t1_.w;                      \
        }                                                                    \
    } while (0)
                LOADB(0, 0);
#pragma unroll
                for (int h = 0; h < 2; ++h) {
                    if (h < 1) LOADB(1, 1);
#pragma unroll
                    for (int q = 0; q < 4; ++q) {
#pragma unroll
                        for (int jr = 0; jr < 4; ++jr) {
                            const int j = 3 - jr;
                            const int t = ttop - (16 * h + 4 * q + jr);
                            const float lpb = pb[h][q][j];
                            const float lpy = py[h][q][j];
                            dp_step<true>(bA, bB, b0, lpb, lpy, skipb, lgrp, l,
                                          (t >= 512) & (t <= xl - 2));
                            const bool ss = (t == xl - 1);
                            bA = ss ? ((l == ls) ? lpb : NEGV) : bA;
                            bB = ss ? ((l == ls) ? lpy : NEGV) : bB;
                            b0 = ss ? NEGV : b0;
                        }
                    }
                }
#undef LOADB
            } else {
                // fast 2-step windows (descending t; lp0 = higher t)
                float pb[2][4][4], py[2][4][4], ph[2][4][4];
#define LOADWB(H, D)                                                         \
    do {                                                                     \
        _Pragma("unroll") for (int q_ = 0; q_ < 4; ++q_) {                   \
            const int rb_ = (7 - 4 * (H) - q_) * kRow;                       \
            const float4 t0_ = *(const float4*)&B[rb_];                      \
            const float4 t1_ = *(const float4*)&B[rb_ + 256 - 4 * l];        \
            const float4 t2_ = *(const float4*)&B[rb_ + im1b];               \
            pb[D][q_][0] = t0_.x; pb[D][q_][1] = t0_.y;                      \
            pb[D][q_][2] = t0_.z; pb[D][q_][3] = t0_.w;                      \
            py[D][q_][0] = t1_.x; py[D][q_][1] = t1_.y;                      \
            py[D][q_][2] = t1_.z; py[D][q_][3] = t1_.w;                      \
            ph[D][q_][0] = t2_.x; ph[D][q_][1] = t2_.y;                      \
            ph[D][q_][2] = t2_.z; ph[D][q_][3] = t2_.w;                      \
        }                                                                    \
    } while (0)
                LOADWB(0, 0);
#pragma unroll
                for (int h = 0; h < 2; ++h) {
                    if (h < 1) LOADWB(1, 1);
#pragma unroll
                    for (int q = 0; q < 4; ++q) {
                        win_step(bA, bB, b0, pb[h][q][3], py[h][q][3],
                                 pb[h][q][2], py[h][q][2], ph[h][q][3], skf,
                                 skm1f, og2, og4, e3g, lgrp, l);
                        win_step(bA, bB, b0, pb[h][q][1], py[h][q][1],
                                 pb[h][q][0], py[h][q][0], ph[h][q][1], skf,
                                 skm1f, og2, og4, e3g, lgrp, l);
                    }
                }
#undef LOADWB
            }
            __syncthreads();
        }
        // gamma_511[s]: one more mirror step with lp = 0 (unconditional).
        dp_step<false>(bA, bB, b0, 0.0f, 0.0f, skipb, lgrp, l, true);
        st_b[128 - 2 * l] = bA;
        st_b[127 - 2 * l] = bB;
        if (l == 0) st_b[0] = b0;
        __syncthreads();
    } else {
        // ---------------- STAGERS ----------------
        const bool isF = wid < 5;
        for (int c = 0; c < kNCH; ++c) {
            if (c + 1 < kNCH) stage(c + 1, (c + 1) & 1, isF);
            __syncthreads();
        }
        __syncthreads();  // match the post-loop barrier
    }
}

// Fallback DP (no gather workspace): log-domain, gathers raw logits. Slow but correct.
template <int PFB>
__global__ __launch_bounds__(64) void k_dp_fb(const float* __restrict__ logits,
                                              const float* __restrict__ lsearr,
                                              const int* __restrict__ y,
                                              const int* __restrict__ xlens,
                                              const int* __restrict__ ylens,
                                              float* __restrict__ nll_out) {
    const int n = blockIdx.x;
    const int l = threadIdx.x;
    const int yl = ylens[n];
    const int xl = xlens[n];
    const int ycur = y[(n << 6) + l];
    const int yprev = __shfl_up(ycur, 1);
    const bool skip = (l >= 1) && (ycur != yprev);

    auto load_lp = [&](int t, float& lpb, float& lpy) {
        const float* p = logits + ((size_t)t * kN + n) * kC;
        const float d = lsearr[t * kN + n];
        lpb = p[0] - d;
        lpy = p[ycur] - d;
    };

    float lpb0, lpy0;
    load_lp(0, lpb0, lpy0);
    float aA = (l == 0) ? lpb0 : NEGV;
    float aB = (l == 0) ? lpy0 : NEGV;
    float aC = NEGV;

    float pb[PFB], py[PFB];
#pragma unroll
    for (int k = 0; k < PFB; ++k) load_lp(1 + k, pb[k], py[k]);

    for (int tb = 1; tb < kT; tb += PFB) {
#pragma unroll
        for (int k = 0; k < PFB; ++k) {
            const int t = tb + k;
            if (t < kT) {
                const float lpb = pb[k], lpy = py[k];
                if (t + PFB < kT) load_lp(t + PFB, pb[k], py[k]);
                float am1 = __shfl_up(aB, 1);
                if (l == 0) am1 = NEGV;
                const float nA = lpb + lse2_e(aA, am1);
                const float nB = lpy + lse3_e(aB, aA, skip ? am1 : NEGV);
                float nC = aC;
                if (l == 63) nC = lpb + lse2_e(aC, aB);
                if (t < xl) { aA = nA; aB = nB; aC = nC; }
            }
        }
    }

    __shared__ float st[130];
    st[2 * l] = aA;
    st[2 * l + 1] = aB;
    if (l == 63) st[128] = aC;
    __syncthreads();
    if (l == 0) {
        const int end = 2 * yl;
        float nll = -lse2_e(st[end], st[end - 1]);
        if (!(isfinite(nll) && nll < 1e29f)) nll = 0.0f;
        nll_out[n] = nll / (float)yl;
    }
}

__global__ __launch_bounds__(128) void k_reduce(const float* __restrict__ nll,
                                                float* __restrict__ out) {
    const int tid = threadIdx.x;
    float v = nll[tid];
#pragma unroll
    for (int o = 32; o > 0; o >>= 1) v += __shfl_xor(v, o);
    __shared__ float partial[2];
    if ((tid & 63) == 0) partial[tid >> 6] = v;
    __syncthreads();
    if (tid == 0) out[0] = (partial[0] + partial[1]) * (1.0f / (float)kN);
}

extern "C" void kernel_launch(void* const* d_in, const int* in_sizes, int n_in,
                              void* d_out, int out_size, void* d_ws, size_t ws_size,
                              hipStream_t stream) {
    const float* logits = (const float*)d_in[0];
    const int* y = (const int*)d_in[1];
    const int* xlens = (const int*)d_in[2];
    const int* ylens = (const int*)d_in[3];
    float* out = (float*)d_out;

    const size_t need_full =
        (size_t)kN * (kT / 4) * kRow * sizeof(float) + kN * sizeof(float);
    const int rows = kT * kN;

    if (ws_size >= need_full) {
        float* lpg = (float*)d_ws;
        float* nll = lpg + (size_t)kN * (kT / 4) * kRow;
        k_lse<true><<<rows / 4, 256, 0, stream>>>(logits, y, lpg, nullptr);
        k_dp_split<<<kN, 512, 0, stream>>>(lpg, y, xlens, ylens, nll);
        k_reduce<<<1, kN, 0, stream>>>(nll, out);
    } else {
        float* lsearr = (float*)d_ws;
        float* nll = lsearr + (size_t)rows;
        k_lse<false><<<rows / 4, 256, 0, stream>>>(logits, y, nullptr, lsearr);
        k_dp_fb<8><<<kN, 64, 0, stream>>>(logits, lsearr, y, xlens, ylens, nll);
        k_reduce<<<1, kN, 0, stream>>>(nll, out);
    }
}

// Round 14
// 117.761 us; speedup vs baseline: 1.0480x; 1.0480x over previous
//
#include <hip/hip_runtime.h>
#include <math.h>

// CTC loss forward: T=1024, N=128, C=256, S=64, L=2S+1=129, blank=0.
constexpr int kT = 1024;
constexpr int kN = 128;
constexpr int kC = 256;
constexpr float NEGV = -1e30f;
constexpr int kRow = 260;            // floats per t4-group: 65 states x 4 t's
constexpr int kRowB = kRow * 4;      // 1040 bytes
constexpr int kCH = 32;              // t-steps per chunk per direction
constexpr int kNCH = 512 / kCH;      // 16 chunks per direction
constexpr int kChF = 8 * kRow;       // 2080 floats per chunk (8 t4-groups)
constexpr int kChB = kChF * 4;       // 8320 bytes
constexpr int SENT = -(1 << 28);     // dead-state exponent sentinel
constexpr float LN2 = 0.6931471805599453f;

#if __has_builtin(__builtin_amdgcn_exp2f)
#define EXP2(x) __builtin_amdgcn_exp2f(x)
#else
#define EXP2(x) exp2f(x)
#endif
#if __has_builtin(__builtin_amdgcn_logf)
#define LOG2(x) __builtin_amdgcn_logf(x)
#else
#define LOG2(x) log2f(x)
#endif

__device__ __forceinline__ float fxm(float x) {
#if __has_builtin(__builtin_amdgcn_frexp_mantf)
    return __builtin_amdgcn_frexp_mantf(x);
#else
    int e; return frexpf(x, &e);
#endif
}
__device__ __forceinline__ int fxe(float x) {
#if __has_builtin(__builtin_amdgcn_frexp_expf)
    return __builtin_amdgcn_frexp_expf(x);
#else
    int e; frexpf(x, &e); return e;
#endif
}
__device__ __forceinline__ float ldx(float x, int e) {
#if __has_builtin(__builtin_amdgcn_ldexpf)
    return __builtin_amdgcn_ldexpf(x, e);
#else
    return ldexpf(x, e);
#endif
}

struct TrueT { static constexpr bool value = true; };
struct FalseT { static constexpr bool value = false; };

__device__ __forceinline__ float lse2_2(float a, float b) {  // log2(2^a + 2^b)
    const float m = fmaxf(a, b);
    const float d = fminf(a, b) - m;
    return m + LOG2(1.0f + EXP2(d));
}

__device__ __forceinline__ float lse2_e(float a, float b) {  // ln(e^a + e^b)
    const float m = fmaxf(a, b);
    return m + __logf(1.0f + __expf(fminf(a, b) - m));
}

__device__ __forceinline__ float lse3_e(float a, float b, float c) {
    const float m = fmaxf(fmaxf(a, b), c);
    return m + __logf(__expf(a - m) + __expf(b - m) + __expf(c - m));
}

// Kernel 1: per-row softmax over C=256. GATHER mode: block = (n, t4) covers
// 4 consecutive t for one n; writes PROBABILITIES of the 65 needed classes in
// blocked-transposed layout lpg[n][t4][s][j] (s=0 blank; j=t&3), via LDS.
template <bool GATHER>
__global__ __launch_bounds__(256) void k_lse(const float* __restrict__ logits,
                                             const int* __restrict__ y,
                                             float* __restrict__ lpg,
                                             float* __restrict__ lse_out) {
    __shared__ float srow[4][kC];
    __shared__ float sT[4][65];
    const int w = threadIdx.x >> 6;
    const int lane = threadIdx.x & 63;
    const int n = blockIdx.x & (kN - 1);
    const int t4 = blockIdx.x >> 7;
    const int t = t4 * 4 + w;
    const int row = t * kN + n;

    const float4 v = reinterpret_cast<const float4*>(logits + (size_t)row * kC)[lane];
    float m = fmaxf(fmaxf(v.x, v.y), fmaxf(v.z, v.w));
#pragma unroll
    for (int o = 32; o > 0; o >>= 1) m = fmaxf(m, __shfl_xor(m, o));
    float s = __expf(v.x - m) + __expf(v.y - m) + __expf(v.z - m) + __expf(v.w - m);
#pragma unroll
    for (int o = 32; o > 0; o >>= 1) s += __shfl_xor(s, o);

    if (GATHER) {
        const float rs = 1.0f / s;
        float* sr = srow[w];
        reinterpret_cast<float4*>(sr)[lane] = v;
        const int cls = y[(n << 6) + lane];  // labels in [1, C)
        sT[w][1 + lane] = __expf(sr[cls] - m) * rs;      // prob of label
        if (lane == 0) sT[w][0] = __expf(v.x - m) * rs;  // prob of blank
        __syncthreads();
        float* op = lpg + (size_t)n * (kT / 4) * kRow + (size_t)t4 * kRow;
        const int tid = threadIdx.x;
        op[tid] = sT[tid & 3][tid >> 2];            // idx = s*4 + j
        if (tid < 4) op[256 + tid] = sT[tid][64];   // s = 64, j = tid
    } else {
        if (lane == 0) lse_out[row] = m + __logf(s);
    }
}

// row_shr:1 with readlane-fed boundaries (validated r6/r7): lane l <- x[l-1];
// lane 0 <- x[63] (wrap); row heads 16/32/48 <- x[15/31/47].
__device__ __forceinline__ int row_shr1_i(int xi, int lgrp) {
    const int b15 = __builtin_amdgcn_readlane(xi, 15);
    const int b31 = __builtin_amdgcn_readlane(xi, 31);
    const int b47 = __builtin_amdgcn_readlane(xi, 47);
    const int b63 = __builtin_amdgcn_readlane(xi, 63);
    const int bnd = (lgrp == 0) ? b63 : (lgrp == 1) ? b15 : (lgrp == 2) ? b31 : b47;
    return __builtin_amdgcn_update_dpp(bnd, xi, 0x111, 0xF, 0xF, false);
}
__device__ __forceinline__ float row_shr1_f(float x, int lgrp) {
    return __int_as_float(row_shr1_i(__float_as_int(x), lgrp));
}

// One DP step in per-state (m,s) exponent/mantissa form: value = s * 2^m,
// s in [0.5,1) or exactly 0 (dead, with m == SENT). NO transcendentals:
// pivot = int max, scaling = v_ldexp (exact), renorm = v_frexp. Semantics
// identical to the validated r7/r11 log-domain dp_step:
//   fwd: A,B = states 2l, 2l+1; C = state 128 (lane 0); shuffle = B[l-1],
//        wrap lane0 <- B[63].  bwd (reversed lane map): exact mirror.
template <bool FRZ>
__device__ __forceinline__ void ms_step(int& mA, float& sA, int& mB, float& sB,
                                        int& mC, float& sC, float Pb, float Py,
                                        bool skip, int lgrp, int l, bool commit) {
    const int m1 = row_shr1_i(mB, lgrp);
    const float s1 = row_shr1_f(sB, lgrp);
    // odd state: nB = Py * (B + A + skip*Bm1)
    const int msk = skip ? m1 : SENT;
    const int p = max(max(mB, mA), msk);
    const float tB = ldx(sB, mB - p);
    const float tA = ldx(sA, mA - p);
    const float tS = ldx(s1, msk - p);
    const float v = Py * ((tB + tA) + tS);
    const int nmB = p + fxe(v);
    const float nsB = fxm(v);
    // even state / extra state share one 2-term sum (lane 0's slot computes C)
    const int um = (l == 0) ? mC : mA;
    const float us = (l == 0) ? sC : sA;
    const int q = max(um, m1);
    const float w = Pb * (ldx(us, um - q) + ldx(s1, m1 - q));
    const int mE = q + fxe(w);
    const float sE = fxm(w);
    // lane 0's own state 0: self-path only
    const float w0 = Pb * sA;
    const int nmA = (l == 0) ? (mA + fxe(w0)) : mE;
    const float nsA = (l == 0) ? fxm(w0) : sE;
    const int nmC = mE;
    const float nsC = sE;
    if (FRZ) {
        mA = commit ? nmA : mA; sA = commit ? nsA : sA;
        mB = commit ? nmB : mB; sB = commit ? nsB : sB;
        mC = commit ? nmC : mC; sC = commit ? nsC : sC;
    } else {
        mA = nmA; sA = nsA; mB = nmB; sB = nsB; mC = nmC; sC = nsC;
    }
}

__device__ __forceinline__ float ms2log(int m, float s) {  // -> log2 value
    return (s > 0.0f) ? ((float)m + LOG2(s)) : NEGV;
}

// Kernel 2: split fwd/bwd DP in (m,s) form. One block per batch item, 8 waves:
// w0 = alpha (t=1..511), w1 = beta (t=1023..512, reversed lane map), w2-4 /
// w5-7 DMA-stage the fwd / bwd prob streams. Merge:
// nll = -lse_s(alpha_511[s] + gamma_511[s]).
__global__ __launch_bounds__(512) void k_dp_split(const float* __restrict__ lpg,
                                                  const int* __restrict__ y,
                                                  const int* __restrict__ xlens,
                                                  const int* __restrict__ ylens,
                                                  float* __restrict__ nll_out) {
    __shared__ alignas(16) float sbf[2][kChF];
    __shared__ alignas(16) float sbb[2][kChF];
    __shared__ float st_f[130];
    __shared__ float st_b[130];
    const int n = blockIdx.x;
    const int wid = threadIdx.x >> 6;
    const int l = threadIdx.x & 63;
    const int lgrp = l >> 4;
    const char* src = (const char*)(lpg + (size_t)n * (kT / 4) * kRow);

    auto stage = [&](int c, int b, bool isF) {
        const int widx = isF ? (wid - 2) : (wid - 5);
        const long off = isF ? (long)c * kChB : (long)(256 - 8 * (c + 1)) * kRowB;
        const char* gs = src + off;
        char* ls = (char*)(isF ? &sbf[b][0] : &sbb[b][0]);
#pragma unroll
        for (int r = 0; r < 3; ++r) {
            const int wi = widx * 64 + r * 192;  // wave-uniform word index
            if (wi + l < kChB / 16) {
                __builtin_amdgcn_global_load_lds(
                    (const __attribute__((address_space(1))) void*)(gs + (size_t)(wi + l) * 16),
                    (__attribute__((address_space(3))) void*)(ls + (size_t)wi * 16), 16, 0, 0);
            }
        }
    };

    if (wid >= 2) stage(0, 0, wid < 5);
    __syncthreads();

    const int yl = ylens[n];
    const int xl = xlens[n];

    if (wid == 0) {
        // ---------------- FORWARD: alpha, t = 1..511 ----------------
        const int ycur = y[(n << 6) + l];
        const int yprev = __shfl_up(ycur, 1);
        const bool skip = (l >= 1) && (ycur != yprev);
        const float P0b = sbf[0][0], P0y = sbf[0][4];
        int mA = (l == 0) ? fxe(P0b) : SENT;
        float sA = (l == 0) ? fxm(P0b) : 0.0f;
        int mB = (l == 0) ? fxe(P0y) : SENT;
        float sB = (l == 0) ? fxm(P0y) : 0.0f;
        int mC = SENT;
        float sC = 0.0f;

        for (int c = 0; c < kNCH; ++c) {
            const float* B = sbf[c & 1];
            const int tb0 = c * kCH;
            auto body = [&](auto frzc) {
                constexpr bool FRZV = decltype(frzc)::value;
                float pb[2][4][4], py[2][4][4];
#define LOADF(H, D)                                                          \
    do {                                                                     \
        _Pragma("unroll") for (int q_ = 0; q_ < 4; ++q_) {                   \
            const int rb_ = (4 * (H) + q_) * kRow;                           \
            const float4 t0_ = *(const float4*)&B[rb_];                      \
            const float4 t1_ = *(const float4*)&B[rb_ + 4 + 4 * l];          \
            pb[D][q_][0] = t0_.x; pb[D][q_][1] = t0_.y;                      \
            pb[D][q_][2] = t0_.z; pb[D][q_][3] = t0_.w;                      \
            py[D][q_][0] = t1_.x; py[D][q_][1] = t1_.y;                      \
            py[D][q_][2] = t1_.z; py[D][q_][3] = t1_.w;                      \
        }                                                                    \
    } while (0)
                LOADF(0, 0);
#pragma unroll
                for (int h = 0; h < 2; ++h) {
                    if (h < 1) LOADF(1, 1);
#pragma unroll
                    for (int q = 0; q < 4; ++q) {
#pragma unroll
                        for (int j = 0; j < 4; ++j) {
                            const int t = tb0 + 16 * h + 4 * q + j;
                            ms_step<FRZV>(mA, sA, mB, sB, mC, sC, pb[h][q][j],
                                          py[h][q][j], skip, lgrp, l,
                                          (t > 0) & (t < xl));
                        }
                    }
                }
#undef LOADF
            };
            if (c == 0 || xl < 512) body(TrueT{});
            else body(FalseT{});
            __syncthreads();
        }
        st_f[2 * l] = ms2log(mA, sA);
        st_f[2 * l + 1] = ms2log(mB, sB);
        if (l == 0) st_f[128] = ms2log(mC, sC);
        __syncthreads();

        // ---------------- MERGE ----------------
        const float v0 = st_f[l] + st_b[l];
        const float v1 = st_f[64 + l] + st_b[64 + l];
        const float v2 = (l == 0) ? (st_f[128] + st_b[128]) : NEGV;
        float mm = fmaxf(fmaxf(v0, v1), v2);
#pragma unroll
        for (int o = 32; o > 0; o >>= 1) mm = fmaxf(mm, __shfl_xor(mm, o));
        float sm = EXP2(v0 - mm) + EXP2(v1 - mm) + EXP2(v2 - mm);
#pragma unroll
        for (int o = 32; o > 0; o >>= 1) sm += __shfl_xor(sm, o);
        if (l == 0) {
            float nll;
            if (xl <= 512) {  // beta segment empty: read frozen alpha directly
                nll = -lse2_2(st_f[2 * yl], st_f[2 * yl - 1]) * LN2;
            } else {
                nll = -(mm + LOG2(sm)) * LN2;
            }
            if (!(isfinite(nll) && nll < 1e29f)) nll = 0.0f;  // zero_infinity
            nll_out[n] = nll / (float)yl;
        }
    } else if (wid == 1) {
        // ---------------- BACKWARD: beta, t = 1023..512 (reversed lanes) ----
        // lane l owns states (128-2l, 127-2l); state 0 in lane 0's extra slot.
        const int ycb = y[(n << 6) + 63 - l];     // label of state 127-2l
        const int yup = __shfl_up(ycb, 1);
        const bool skipb = (l >= 1) && (ycb != yup);
        const int ls = 64 - yl;                   // seed lane (yl=64 -> 0)
        int mA = SENT, mB = SENT, m0 = SENT;
        float sA = 0.0f, sB = 0.0f, s0 = 0.0f;

        for (int c = 0; c < kNCH; ++c) {
            const float* B = sbb[c & 1];
            const int ttop = 1023 - kCH * c;      // t of first (descending) slot
            auto body = [&](auto frzc) {
                constexpr bool FRZV = decltype(frzc)::value;
                float pb[2][4][4], py[2][4][4];
#define LOADB(H, D)                                                          \
    do {                                                                     \
        _Pragma("unroll") for (int q_ = 0; q_ < 4; ++q_) {                   \
            const int rb_ = (7 - 4 * (H) - q_) * kRow;                       \
            const float4 t0_ = *(const float4*)&B[rb_];                      \
            const float4 t1_ = *(const float4*)&B[rb_ + 256 - 4 * l];        \
            pb[D][q_][0] = t0_.x; pb[D][q_][1] = t0_.y;                      \
            pb[D][q_][2] = t0_.z; pb[D][q_][3] = t0_.w;                      \
            py[D][q_][0] = t1_.x; py[D][q_][1] = t1_.y;                      \
            py[D][q_][2] = t1_.z; py[D][q_][3] = t1_.w;                      \
        }                                                                    \
    } while (0)
                LOADB(0, 0);
#pragma unroll
                for (int h = 0; h < 2; ++h) {
                    if (h < 1) LOADB(1, 1);
#pragma unroll
                    for (int q = 0; q < 4; ++q) {
#pragma unroll
                        for (int jr = 0; jr < 4; ++jr) {
                            const int j = 3 - jr;
                            const int t = ttop - (16 * h + 4 * q + jr);
                            const float Pb = pb[h][q][j];
                            const float Py = py[h][q][j];
                            ms_step<FRZV>(mA, sA, mB, sB, m0, s0, Pb, Py, skipb,
                                          lgrp, l, (t >= 512) & (t <= xl - 2));
                            if (FRZV) {  // seed beta_{xl-1} in-stream
                                const bool ss = (t == xl - 1);
                                const bool sl = ss & (l == ls);
                                mA = ss ? (sl ? fxe(Pb) : SENT) : mA;
                                sA = ss ? (sl ? fxm(Pb) : 0.0f) : sA;
                                mB = ss ? (sl ? fxe(Py) : SENT) : mB;
                                sB = ss ? (sl ? fxm(Py) : 0.0f) : sB;
                                m0 = ss ? SENT : m0;
                                s0 = ss ? 0.0f : s0;
                            }
                        }
                    }
                }
#undef LOADB
            };
            if (c == 0 || xl < kT) body(TrueT{});
            else body(FalseT{});
            __syncthreads();
        }
        // gamma_511[s]: one more mirror step with P = 1 (unconditional).
        ms_step<false>(mA, sA, mB, sB, m0, s0, 1.0f, 1.0f, skipb, lgrp, l, true);
        st_b[128 - 2 * l] = ms2log(mA, sA);
        st_b[127 - 2 * l] = ms2log(mB, sB);
        if (l == 0) st_b[0] = ms2log(m0, s0);
        __syncthreads();
    } else {
        // ---------------- STAGERS ----------------
        const bool isF = wid < 5;
        for (int c = 0; c < kNCH; ++c) {
            if (c + 1 < kNCH) stage(c + 1, (c + 1) & 1, isF);
            __syncthreads();
        }
        __syncthreads();  // match the post-loop barrier
    }
}

// Fallback DP (no gather workspace): log-domain, gathers raw logits. Slow but correct.
template <int PFB>
__global__ __launch_bounds__(64) void k_dp_fb(const float* __restrict__ logits,
                                              const float* __restrict__ lsearr,
                                              const int* __restrict__ y,
                                              const int* __restrict__ xlens,
                                              const int* __restrict__ ylens,
                                              float* __restrict__ nll_out) {
    const int n = blockIdx.x;
    const int l = threadIdx.x;
    const int yl = ylens[n];
    const int xl = xlens[n];
    const int ycur = y[(n << 6) + l];
    const int yprev = __shfl_up(ycur, 1);
    const bool skip = (l >= 1) && (ycur != yprev);

    auto load_lp = [&](int t, float& lpb, float& lpy) {
        const float* p = logits + ((size_t)t * kN + n) * kC;
        const float d = lsearr[t * kN + n];
        lpb = p[0] - d;
        lpy = p[ycur] - d;
    };

    float lpb0, lpy0;
    load_lp(0, lpb0, lpy0);
    float aA = (l == 0) ? lpb0 : NEGV;
    float aB = (l == 0) ? lpy0 : NEGV;
    float aC = NEGV;

    float pb[PFB], py[PFB];
#pragma unroll
    for (int k = 0; k < PFB; ++k) load_lp(1 + k, pb[k], py[k]);

    for (int tb = 1; tb < kT; tb += PFB) {
#pragma unroll
        for (int k = 0; k < PFB; ++k) {
            const int t = tb + k;
            if (t < kT) {
                const float lpb = pb[k], lpy = py[k];
                if (t + PFB < kT) load_lp(t + PFB, pb[k], py[k]);
                float am1 = __shfl_up(aB, 1);
                if (l == 0) am1 = NEGV;
                const float nA = lpb + lse2_e(aA, am1);
                const float nB = lpy + lse3_e(aB, aA, skip ? am1 : NEGV);
                float nC = aC;
                if (l == 63) nC = lpb + lse2_e(aC, aB);
                if (t < xl) { aA = nA; aB = nB; aC = nC; }
            }
        }
    }

    __shared__ float st[130];
    st[2 * l] = aA;
    st[2 * l + 1] = aB;
    if (l == 63) st[128] = aC;
    __syncthreads();
    if (l == 0) {
        const int end = 2 * yl;
        float nll = -lse2_e(st[end], st[end - 1]);
        if (!(isfinite(nll) && nll < 1e29f)) nll = 0.0f;
        nll_out[n] = nll / (float)yl;
    }
}

__global__ __launch_bounds__(128) void k_reduce(const float* __restrict__ nll,
                                                float* __restrict__ out) {
    const int tid = threadIdx.x;
    float v = nll[tid];
#pragma unroll
    for (int o = 32; o > 0; o >>= 1) v += __shfl_xor(v, o);
    __shared__ float partial[2];
    if ((tid & 63) == 0) partial[tid >> 6] = v;
    __syncthreads();
    if (tid == 0) out[0] = (partial[0] + partial[1]) * (1.0f / (float)kN);
}

extern "C" void kernel_launch(void* const* d_in, const int* in_sizes, int n_in,
                              void* d_out, int out_size, void* d_ws, size_t ws_size,
                              hipStream_t stream) {
    const float* logits = (const float*)d_in[0];
    const int* y = (const int*)d_in[1];
    const int* xlens = (const int*)d_in[2];
    const int* ylens = (const int*)d_in[3];
    float* out = (float*)d_out;

    const size_t need_full =
        (size_t)kN * (kT / 4) * kRow * sizeof(float) + kN * sizeof(float);
    const int rows = kT * kN;

    if (ws_size >= need_full) {
        float* lpg = (float*)d_ws;
        float* nll = lpg + (size_t)kN * (kT / 4) * kRow;
        k_lse<true><<<rows / 4, 256, 0, stream>>>(logits, y, lpg, nullptr);
        k_dp_split<<<kN, 512, 0, stream>>>(lpg, y, xlens, ylens, nll);
        k_reduce<<<1, kN, 0, stream>>>(nll, out);
    } else {
        float* lsearr = (float*)d_ws;
        float* nll = lsearr + (size_t)rows;
        k_lse<false><<<rows / 4, 256, 0, stream>>>(logits, y, nullptr, lsearr);
        k_dp_fb<8><<<kN, 64, 0, stream>>>(logits, lsearr, y, xlens, ylens, nll);
        k_reduce<<<1, kN, 0, stream>>>(nll, out);
    }
}

// Round 15
// 96.393 us; speedup vs baseline: 1.2803x; 1.2217x over previous
//
#include <hip/hip_runtime.h>
#include <math.h>

// CTC loss forward: T=1024, N=128, C=256, S=64, L=2S+1=129, blank=0.
constexpr int kT = 1024;
constexpr int kN = 128;
constexpr int kC = 256;
constexpr float NEGV = -1e30f;
constexpr int kRow = 260;            // floats per t4-group: 65 states x 4 t's
constexpr int kRowB = kRow * 4;      // 1040 bytes
constexpr int kCH = 32;              // t-steps per chunk per direction
constexpr int kNCH = 512 / kCH;      // 16 chunks per direction
constexpr int kChF = 8 * kRow;       // 2080 floats per chunk (8 t4-groups)
constexpr int kChB = kChF * 4;       // 8320 bytes
constexpr float LOG2E = 1.4426950408889634f;
constexpr float LN2 = 0.6931471805599453f;

#if __has_builtin(__builtin_amdgcn_exp2f)
#define EXP2(x) __builtin_amdgcn_exp2f(x)
#else
#define EXP2(x) exp2f(x)
#endif
#if __has_builtin(__builtin_amdgcn_logf)
#define LOG2(x) __builtin_amdgcn_logf(x)
#else
#define LOG2(x) log2f(x)
#endif

struct TrueT { static constexpr bool value = true; };
struct FalseT { static constexpr bool value = false; };

__device__ __forceinline__ float lse2_2(float a, float b) {  // log2(2^a + 2^b)
    const float m = fmaxf(a, b);
    const float d = fminf(a, b) - m;
    return m + LOG2(1.0f + EXP2(d));
}

__device__ __forceinline__ float lse2_e(float a, float b) {  // ln(e^a + e^b)
    const float m = fmaxf(a, b);
    return m + __logf(1.0f + __expf(fminf(a, b) - m));
}

__device__ __forceinline__ float lse3_e(float a, float b, float c) {
    const float m = fmaxf(fmaxf(a, b), c);
    return m + __logf(__expf(a - m) + __expf(b - m) + __expf(c - m));
}

// Kernel 1: per-row logsumexp over C=256. GATHER mode: block = (n, t4) covers
// 4 consecutive t for one n; writes BASE-2 log-probs in blocked-transposed
// layout lpg[n][t4][s][j] (s=0 blank, s=1+k label k; j=t&3), coalesced via LDS.
template <bool GATHER>
__global__ __launch_bounds__(256) void k_lse(const float* __restrict__ logits,
                                             const int* __restrict__ y,
                                             float* __restrict__ lpg,
                                             float* __restrict__ lse_out) {
    __shared__ float srow[4][kC];
    __shared__ float sT[4][65];
    const int w = threadIdx.x >> 6;
    const int lane = threadIdx.x & 63;
    const int n = blockIdx.x & (kN - 1);
    const int t4 = blockIdx.x >> 7;
    const int t = t4 * 4 + w;
    const int row = t * kN + n;

    const float4 v = reinterpret_cast<const float4*>(logits + (size_t)row * kC)[lane];
    float m = fmaxf(fmaxf(v.x, v.y), fmaxf(v.z, v.w));
#pragma unroll
    for (int o = 32; o > 0; o >>= 1) m = fmaxf(m, __shfl_xor(m, o));
    float s = __expf(v.x - m) + __expf(v.y - m) + __expf(v.z - m) + __expf(v.w - m);
#pragma unroll
    for (int o = 32; o > 0; o >>= 1) s += __shfl_xor(s, o);

    if (GATHER) {
        const float log2s = LOG2(s);
        float* sr = srow[w];
        reinterpret_cast<float4*>(sr)[lane] = v;
        const int cls = y[(n << 6) + lane];  // labels in [1, C)
        sT[w][1 + lane] = (sr[cls] - m) * LOG2E - log2s;
        if (lane == 0) sT[w][0] = (v.x - m) * LOG2E - log2s;  // blank
        __syncthreads();
        float* op = lpg + (size_t)n * (kT / 4) * kRow + (size_t)t4 * kRow;
        const int tid = threadIdx.x;
        op[tid] = sT[tid & 3][tid >> 2];            // idx = s*4 + j
        if (tid < 4) op[256 + tid] = sT[tid][64];   // s = 64, j = tid
    } else {
        if (lane == 0) lse_out[row] = m + __logf(s);
    }
}

// One DP step, log2 domain (validated r7/r11). Works for BOTH directions:
// fwd: A,B = alpha[2l], alpha[2l+1]; C = alpha[128] (lane 0); shuffle = B[l-1],
//      wrap lane0 <- B[63].
// bwd (reversed lane map): A,B = beta[128-2l], beta[127-2l]; C = beta[0]
//      (lane 0); identical shuffle/boundary structure (exact mirror).
template <bool FRZ>
__device__ __forceinline__ void dp_step(float& A, float& B, float& C,
                                        float lpb, float lpy, bool skip,
                                        int lgrp, int l, bool commit) {
    const int bi = __float_as_int(B);
    const int b15 = __builtin_amdgcn_readlane(bi, 15);
    const int b31 = __builtin_amdgcn_readlane(bi, 31);
    const int b47 = __builtin_amdgcn_readlane(bi, 47);
    const int b63 = __builtin_amdgcn_readlane(bi, 63);
    const int bndi = (lgrp == 0) ? b63 : (lgrp == 1) ? b15 : (lgrp == 2) ? b31 : b47;
    const float am1 = __int_as_float(__builtin_amdgcn_update_dpp(
        bndi, bi, 0x111 /*row_shr:1*/, 0xF, 0xF, false));
    const float am1s = skip ? am1 : NEGV;
    // nB = lpy + lse3(B, A, am1s): med3 2-exp form
    const float x = fmaxf(B, A), yv = fminf(B, A);
    const float mB = fmaxf(x, am1s);
    const float dB1 = fmaxf(yv, fminf(x, am1s)) - mB;  // med - max
    const float dB2 = fminf(yv, am1s) - mB;            // min - max
    const float nB = (lpy + mB) + LOG2(1.0f + (EXP2(dB1) + EXP2(dB2)));
    // even-state / extra-state share one lse2 (lane 0's slot computes C)
    const float u = (l == 0) ? C : A;
    const float mA = fmaxf(u, am1);
    const float lseA = mA + LOG2(1.0f + EXP2(fminf(u, am1) - mA));
    const float nA = lpb + ((l == 0) ? A : lseA);
    const float nC = lpb + lseA;  // meaningful at lane 0 only
    if (FRZ) {
        A = commit ? nA : A;
        B = commit ? nB : B;
        C = commit ? nC : C;
    } else {
        A = nA; B = nB; C = nC;
    }
}

// Kernel 2: split forward/backward DP. One block per batch item, 4 waves:
// w0 = alpha (t=1..511), w1 = beta (t=1023..512, reversed lane map), w2 stages
// the fwd lp stream, w3 the bwd stream. Merge:
// nll = -lse_s(alpha_511[s] + gamma_511[s]).
__global__ __launch_bounds__(256) void k_dp_split(const float* __restrict__ lpg,
                                                  const int* __restrict__ y,
                                                  const int* __restrict__ xlens,
                                                  const int* __restrict__ ylens,
                                                  float* __restrict__ nll_out) {
    __shared__ alignas(16) float sbf[2][kChF];
    __shared__ alignas(16) float sbb[2][kChF];
    __shared__ float st_f[130];
    __shared__ float st_b[130];
    const int n = blockIdx.x;
    const int wid = threadIdx.x >> 6;
    const int l = threadIdx.x & 63;
    const int lgrp = l >> 4;
    const char* src = (const char*)(lpg + (size_t)n * (kT / 4) * kRow);

    auto stage = [&](int c, int b, bool isF) {
        const long off = isF ? (long)c * kChB : (long)(256 - 8 * (c + 1)) * kRowB;
        const char* gs = src + off;
        char* ls = (char*)(isF ? &sbf[b][0] : &sbb[b][0]);
#pragma unroll
        for (int r = 0; r < 9; ++r) {
            const int wi = r * 64;  // wave-uniform word index; kChB/16 = 520 words
            if (wi + l < kChB / 16) {
                __builtin_amdgcn_global_load_lds(
                    (const __attribute__((address_space(1))) void*)(gs + (size_t)(wi + l) * 16),
                    (__attribute__((address_space(3))) void*)(ls + (size_t)wi * 16), 16, 0, 0);
            }
        }
    };

    if (wid >= 2) stage(0, 0, wid == 2);
    __syncthreads();

    const int yl = ylens[n];
    const int xl = xlens[n];

    if (wid == 0) {
        // ---------------- FORWARD: alpha, t = 1..511 ----------------
        const int ycur = y[(n << 6) + l];
        const int yprev = __shfl_up(ycur, 1);
        const bool skip = (l >= 1) && (ycur != yprev);
        float aA = (l == 0) ? sbf[0][0] : NEGV;  // lp[t=0][s=0]
        float aB = (l == 0) ? sbf[0][4] : NEGV;  // lp[t=0][s=1]
        float aC = NEGV;

        for (int c = 0; c < kNCH; ++c) {
            const float* B = sbf[c & 1];
            const int tb0 = c * kCH;
            auto body = [&](auto frzc) {
                constexpr bool FRZV = decltype(frzc)::value;
                float pb[2][4][4], py[2][4][4];
#define LOADF(H, D)                                                          \
    do {                                                                     \
        _Pragma("unroll") for (int q_ = 0; q_ < 4; ++q_) {                   \
            const int rb_ = (4 * (H) + q_) * kRow;                           \
            const float4 t0_ = *(const float4*)&B[rb_];                      \
            const float4 t1_ = *(const float4*)&B[rb_ + 4 + 4 * l];          \
            pb[D][q_][0] = t0_.x; pb[D][q_][1] = t0_.y;                      \
            pb[D][q_][2] = t0_.z; pb[D][q_][3] = t0_.w;                      \
            py[D][q_][0] = t1_.x; py[D][q_][1] = t1_.y;                      \
            py[D][q_][2] = t1_.z; py[D][q_][3] = t1_.w;                      \
        }                                                                    \
    } while (0)
                LOADF(0, 0);
#pragma unroll
                for (int h = 0; h < 2; ++h) {
                    const int cur = h & 1;
                    if (h < 1) LOADF(1, 1);
#pragma unroll
                    for (int q = 0; q < 4; ++q) {
#pragma unroll
                        for (int j = 0; j < 4; ++j) {
                            const int t = tb0 + 16 * h + 4 * q + j;
                            dp_step<FRZV>(aA, aB, aC, pb[cur][q][j], py[cur][q][j],
                                          skip, lgrp, l, (t > 0) & (t < xl));
                        }
                    }
                }
#undef LOADF
            };
            if (c == 0 || xl < 512) body(TrueT{});
            else body(FalseT{});
            __syncthreads();
        }
        st_f[2 * l] = aA;
        st_f[2 * l + 1] = aB;
        if (l == 0) st_f[128] = aC;
        __syncthreads();

        // ---------------- MERGE ----------------
        const float v0 = st_f[l] + st_b[l];
        const float v1 = st_f[64 + l] + st_b[64 + l];
        const float v2 = (l == 0) ? (st_f[128] + st_b[128]) : NEGV;
        float mm = fmaxf(fmaxf(v0, v1), v2);
#pragma unroll
        for (int o = 32; o > 0; o >>= 1) mm = fmaxf(mm, __shfl_xor(mm, o));
        float sm = EXP2(v0 - mm) + EXP2(v1 - mm) + EXP2(v2 - mm);
#pragma unroll
        for (int o = 32; o > 0; o >>= 1) sm += __shfl_xor(sm, o);
        if (l == 0) {
            float nll;
            if (xl <= 512) {  // beta segment empty: read frozen alpha directly
                nll = -lse2_2(st_f[2 * yl], st_f[2 * yl - 1]) * LN2;
            } else {
                nll = -(mm + LOG2(sm)) * LN2;
            }
            if (!(isfinite(nll) && nll < 1e29f)) nll = 0.0f;  // zero_infinity
            nll_out[n] = nll / (float)yl;
        }
    } else if (wid == 1) {
        // ---------------- BACKWARD: beta, t = 1023..512 (reversed lanes) ----
        // lane l owns states (128-2l, 127-2l); state 0 in lane 0's extra slot.
        const int ycb = y[(n << 6) + 63 - l];     // label of state 127-2l
        const int yup = __shfl_up(ycb, 1);        // y[64-l]
        const bool skipb = (l >= 1) && (ycb != yup);
        const int ls = 64 - yl;                   // seed lane (yl=64 -> 0)
        float bA = NEGV, bB = NEGV, b0 = NEGV;

        for (int c = 0; c < kNCH; ++c) {
            const float* B = sbb[c & 1];
            const int ttop = 1023 - kCH * c;      // t of first (descending) slot
            auto body = [&](auto frzc) {
                constexpr bool FRZV = decltype(frzc)::value;
                float pb[2][4][4], py[2][4][4];
#define LOADB(H, D)                                                          \
    do {                                                                     \
        _Pragma("unroll") for (int q_ = 0; q_ < 4; ++q_) {                   \
            const int rb_ = (7 - 4 * (H) - q_) * kRow;                       \
            const float4 t0_ = *(const float4*)&B[rb_];                      \
            const float4 t1_ = *(const float4*)&B[rb_ + 256 - 4 * l];        \
            pb[D][q_][0] = t0_.x; pb[D][q_][1] = t0_.y;                      \
            pb[D][q_][2] = t0_.z; pb[D][q_][3] = t0_.w;                      \
            py[D][q_][0] = t1_.x; py[D][q_][1] = t1_.y;                      \
            py[D][q_][2] = t1_.z; py[D][q_][3] = t1_.w;                      \
        }                                                                    \
    } while (0)
                LOADB(0, 0);
#pragma unroll
                for (int h = 0; h < 2; ++h) {
                    const int cur = h & 1;
                    if (h < 1) LOADB(1, 1);
#pragma unroll
                    for (int q = 0; q < 4; ++q) {
#pragma unroll
                        for (int jr = 0; jr < 4; ++jr) {
                            const int j = 3 - jr;
                            const int t = ttop - (16 * h + 4 * q + jr);
                            const float lpb = pb[cur][q][j];
                            const float lpy = py[cur][q][j];
                            dp_step<FRZV>(bA, bB, b0, lpb, lpy, skipb, lgrp, l,
                                          (t >= 512) & (t <= xl - 2));
                            if (FRZV) {  // seed beta_{xl-1} in-stream
                                const bool ss = (t == xl - 1);
                                bA = ss ? ((l == ls) ? lpb : NEGV) : bA;
                                bB = ss ? ((l == ls) ? lpy : NEGV) : bB;
                                b0 = ss ? NEGV : b0;
                            }
                        }
                    }
                }
#undef LOADB
            };
            if (c == 0 || xl < kT) body(TrueT{});
            else body(FalseT{});
            __syncthreads();
        }
        // gamma_511[s] = lse(beta[s], beta[s+1], allow? beta[s+2]) = one more
        // mirror step with lp = 0 (unconditional).
        dp_step<false>(bA, bB, b0, 0.0f, 0.0f, skipb, lgrp, l, true);
        st_b[128 - 2 * l] = bA;
        st_b[127 - 2 * l] = bB;
        if (l == 0) st_b[0] = b0;
        __syncthreads();
    } else {
        // ---------------- STAGERS (w2 = fwd, w3 = bwd) ----------------
        const bool isF = (wid == 2);
        for (int c = 0; c < kNCH; ++c) {
            if (c + 1 < kNCH) stage(c + 1, (c + 1) & 1, isF);
            __syncthreads();
        }
        __syncthreads();  // match the post-loop barrier
    }
}

// Fallback DP (no gather workspace): log-domain, gathers raw logits. Slow but correct.
template <int PFB>
__global__ __launch_bounds__(64) void k_dp_fb(const float* __restrict__ logits,
                                              const float* __restrict__ lsearr,
                                              const int* __restrict__ y,
                                              const int* __restrict__ xlens,
                                              const int* __restrict__ ylens,
                                              float* __restrict__ nll_out) {
    const int n = blockIdx.x;
    const int l = threadIdx.x;
    const int yl = ylens[n];
    const int xl = xlens[n];
    const int ycur = y[(n << 6) + l];
    const int yprev = __shfl_up(ycur, 1);
    const bool skip = (l >= 1) && (ycur != yprev);

    auto load_lp = [&](int t, float& lpb, float& lpy) {
        const float* p = logits + ((size_t)t * kN + n) * kC;
        const float d = lsearr[t * kN + n];
        lpb = p[0] - d;
        lpy = p[ycur] - d;
    };

    float lpb0, lpy0;
    load_lp(0, lpb0, lpy0);
    float aA = (l == 0) ? lpb0 : NEGV;
    float aB = (l == 0) ? lpy0 : NEGV;
    float aC = NEGV;

    float pb[PFB], py[PFB];
#pragma unroll
    for (int k = 0; k < PFB; ++k) load_lp(1 + k, pb[k], py[k]);

    for (int tb = 1; tb < kT; tb += PFB) {
#pragma unroll
        for (int k = 0; k < PFB; ++k) {
            const int t = tb + k;
            if (t < kT) {
                const float lpb = pb[k], lpy = py[k];
                if (t + PFB < kT) load_lp(t + PFB, pb[k], py[k]);
                float am1 = __shfl_up(aB, 1);
                if (l == 0) am1 = NEGV;
                const float nA = lpb + lse2_e(aA, am1);
                const float nB = lpy + lse3_e(aB, aA, skip ? am1 : NEGV);
                float nC = aC;
                if (l == 63) nC = lpb + lse2_e(aC, aB);
                if (t < xl) { aA = nA; aB = nB; aC = nC; }
            }
        }
    }

    __shared__ float st[130];
    st[2 * l] = aA;
    st[2 * l + 1] = aB;
    if (l == 63) st[128] = aC;
    __syncthreads();
    if (l == 0) {
        const int end = 2 * yl;
        float nll = -lse2_e(st[end], st[end - 1]);
        if (!(isfinite(nll) && nll < 1e29f)) nll = 0.0f;
        nll_out[n] = nll / (float)yl;
    }
}

__global__ __launch_bounds__(128) void k_reduce(const float* __restrict__ nll,
                                                float* __restrict__ out) {
    const int tid = threadIdx.x;
    float v = nll[tid];
#pragma unroll
    for (int o = 32; o > 0; o >>= 1) v += __shfl_xor(v, o);
    __shared__ float partial[2];
    if ((tid & 63) == 0) partial[tid >> 6] = v;
    __syncthreads();
    if (tid == 0) out[0] = (partial[0] + partial[1]) * (1.0f / (float)kN);
}

extern "C" void kernel_launch(void* const* d_in, const int* in_sizes, int n_in,
                              void* d_out, int out_size, void* d_ws, size_t ws_size,
                              hipStream_t stream) {
    const float* logits = (const float*)d_in[0];
    const int* y = (const int*)d_in[1];
    const int* xlens = (const int*)d_in[2];
    const int* ylens = (const int*)d_in[3];
    float* out = (float*)d_out;

    const size_t need_full =
        (size_t)kN * (kT / 4) * kRow * sizeof(float) + kN * sizeof(float);
    const int rows = kT * kN;

    if (ws_size >= need_full) {
        float* lpg = (float*)d_ws;
        float* nll = lpg + (size_t)kN * (kT / 4) * kRow;
        k_lse<true><<<rows / 4, 256, 0, stream>>>(logits, y, lpg, nullptr);
        k_dp_split<<<kN, 256, 0, stream>>>(lpg, y, xlens, ylens, nll);
        k_reduce<<<1, kN, 0, stream>>>(nll, out);
    } else {
        float* lsearr = (float*)d_ws;
        float* nll = lsearr + (size_t)rows;
        k_lse<false><<<rows / 4, 256, 0, stream>>>(logits, y, nullptr, lsearr);
        k_dp_fb<8><<<kN, 64, 0, stream>>>(logits, lsearr, y, xlens, ylens, nll);
        k_reduce<<<1, kN, 0, stream>>>(nll, out);
    }
}